// Round 5
// baseline (264.359 us; speedup 1.0000x reference)
//
#include <hip/hip_runtime.h>
#include <hip/hip_bf16.h>
#include <cstdint>

// B=2, HW=64 -> 128 rows of S=256; M = 32768. D=512, HEADS=8, DK=64,
// 3*H*DK=1536, KSIZE=7. Inputs/outputs fp32; internal compute bf16 MFMA.

typedef __bf16 bf16x8 __attribute__((ext_vector_type(8)));
typedef float f32x4 __attribute__((ext_vector_type(4)));

__device__ __forceinline__ uint16_t f2bf(float f) {
    uint32_t u = __builtin_bit_cast(uint32_t, f);
    return (uint16_t)((u + 0x7fffu + ((u >> 16) & 1u)) >> 16);
}
__device__ __forceinline__ float bflo(uint32_t u) { return __builtin_bit_cast(float, u << 16); }
__device__ __forceinline__ float bfhi(uint32_t u) { return __builtin_bit_cast(float, u & 0xffff0000u); }

__device__ __forceinline__ void unpack8(uint4 v, float* f) {
    f[0] = bflo(v.x); f[1] = bfhi(v.x);
    f[2] = bflo(v.y); f[3] = bfhi(v.y);
    f[4] = bflo(v.z); f[5] = bfhi(v.z);
    f[6] = bflo(v.w); f[7] = bfhi(v.w);
}
__device__ __forceinline__ uint32_t pack2(float a, float b) {
    return (uint32_t)f2bf(a) | ((uint32_t)f2bf(b) << 16);
}

#define GLOAD_LDS16(gp, lp)                                                        \
    __builtin_amdgcn_global_load_lds((const __attribute__((address_space(1))) void*)(gp), \
                                     (__attribute__((address_space(3))) void*)(lp), 16, 0, 0)

// Inline-asm LDS read: invisible to the compiler's waitcnt/alias tracking.
// Volatile asm keeps mutual program order with the waitcnt/barrier asm, so the
// issue/wait counting below is exact. Caller owns lgkmcnt discipline.
__device__ __forceinline__ bf16x8 ds_read16(const uint16_t* p) {
    bf16x8 r;
    asm volatile("ds_read_b128 %0, %1"
                 : "=v"(r)
                 : "v"((const __attribute__((address_space(3))) void*)p));
    return r;
}

// Inline-asm counted global load (vmcnt accounting owned by caller).
__device__ __forceinline__ uint4 gload16(const uint16_t* p) {
    uint4 r;
    asm volatile("global_load_dwordx4 %0, %1, off"
                 : "=v"(r)
                 : "v"((const __attribute__((address_space(1))) void*)p));
    return r;
}

// ---------------------------------------------------------------------------
// fp32 -> bf16 bulk convert, 8 elems/thread
// ---------------------------------------------------------------------------
__global__ void cvt_f32_bf16(const float* __restrict__ in, uint16_t* __restrict__ out, int n8) {
    int i = blockIdx.x * 256 + threadIdx.x;
    if (i >= n8) return;
    const float4* p = (const float4*)in + (size_t)i * 2;
    float4 a = p[0], b = p[1];
    uint4 o;
    o.x = pack2(a.x, a.y);
    o.y = pack2(a.z, a.w);
    o.z = pack2(b.x, b.y);
    o.w = pack2(b.z, b.w);
    *((uint4*)out + i) = o;
}

// ---------------------------------------------------------------------------
// transpose + convert: out[c*R + r] = bf16(in[r*C + c])
// ---------------------------------------------------------------------------
__global__ void transpose_cvt(const float* __restrict__ in, uint16_t* __restrict__ out,
                              int R, int C) {
    int idx = blockIdx.x * 256 + threadIdx.x;
    if (idx >= R * C) return;
    int r = idx / C;
    int c = idx - r * C;
    out[(size_t)c * R + r] = f2bf(in[idx]);
}

// ---------------------------------------------------------------------------
// 256x128-tile bf16 GEMM, BK=32, 2 blocks/CU (the occupancy unlock).
// C[M,N] = A[M,K] @ B[K,N], B given transposed (BT[N,K]).
// 512 threads = 8 waves (4 M-waves x 2 N-waves), per-wave 64x64 output
// (acc[4][4] of 16x16x32 frags = 64 VGPR -> ~120 total -> 16 waves/CU fit
// the 2048-reg pool; LDS 48 KB dbuf -> 2 blocks/CU, 4 waves/SIMD).
//
// LDS layout (per tile): rows packed 2-per-64-elem-line; 16B chunk of
// (row, c) stored at line = row>>1, p = ((row&1)*4 + c) ^ (line&7).
// ds_read_b128 frag reads then hit each 4-bank group with exactly 2 lanes
// (free, m136). DMA dest is linear (chunk d at elem d*8 = lane*16 B); the
// inverse permutation is applied to the per-thread GLOBAL source address
// (both-sides rule #21).
//
// Per K-tile t (buf b = t&1), derived waits, one barrier per tile:
//   stage(t+1 -> buf b^1)  [3 global_load_lds, full tile ahead of the wait]
//   issue B0..3, A0,A1; issue A2,A3          [8 ds_read]
//   lgkmcnt(2) -> B+A01 done -> 8 MFMA (mf0,1)   [A23 in flight]
//   lgkmcnt(0) -> A23 done  -> 8 MFMA (mf2,3)
//   vmcnt(0); s_barrier     [stage landed; all waves done reading buf b]
// Race-safety: reads target buf b only, stages target b^1 only; b^1's last
// readers (tile t-1) drained at their lgkmcnt(0) before tile t-1's barrier.
// Assumes K % 32 == 0, K/32 >= 2 (here K=512 -> NT=16).
// ---------------------------------------------------------------------------
template <bool F32OUT>
__global__ __launch_bounds__(512, 4)
void gemm_mn(const uint16_t* __restrict__ A, const uint16_t* __restrict__ BT,
             void* __restrict__ Cout, int M, int N, int K) {
    // elems: A bufs [0,16384) (2 x 8192), B bufs [16384,24576) (2 x 4096)
    __shared__ __align__(16) uint16_t lds[24576];  // 48 KB

    const int tid  = threadIdx.x;
    const int lane = tid & 63;
    const int wv   = tid >> 6;
    const int r    = lane & 15;
    const int quad = lane >> 4;
    const int wr   = wv >> 1;   // 0..3  (M wave)
    const int wc   = wv & 1;    // 0..1  (N wave)
    const long bm0 = (long)blockIdx.x * 256;
    const long bn0 = (long)blockIdx.y * 128;
    const int NT   = K >> 5;

    // ---- staging: A chunks d0=tid, d1=tid+512 (of 1024); B chunk e0=tid ----
    // chunk d -> line=d>>3, p=d&7, pre=p^(line&7), half=pre>>2, c=pre&3,
    // row=2*line+half, src col = c*8 (within the 32-elem k-slice).
#define SRC_ROWCOL(d_, row_, col_) do {                                                 \
        int ln_ = (d_) >> 3, pre_ = ((d_) & 7) ^ (ln_ & 7);                             \
        row_ = 2 * ln_ + (pre_ >> 2);                                                   \
        col_ = (pre_ & 3) * 8;                                                          \
    } while (0)
    int rA0, cA0, rA1, cA1, rB0, cB0;
    SRC_ROWCOL(tid,       rA0, cA0);
    SRC_ROWCOL(tid + 512, rA1, cA1);
    SRC_ROWCOL(tid,       rB0, cB0);
    const uint16_t* pA0 = A  + (bm0 + rA0) * (long)K + cA0;
    const uint16_t* pA1 = A  + (bm0 + rA1) * (long)K + cA1;
    const uint16_t* pB0 = BT + (bn0 + rB0) * (long)K + cB0;
#undef SRC_ROWCOL

#define STAGE(b_, t_) do {                                                              \
        GLOAD_LDS16(pA0 + (t_) * 32, &lds[(b_) * 8192 + tid * 8]);                      \
        GLOAD_LDS16(pA1 + (t_) * 32, &lds[(b_) * 8192 + (tid + 512) * 8]);              \
        GLOAD_LDS16(pB0 + (t_) * 32, &lds[16384 + (b_) * 4096 + tid * 8]);              \
    } while (0)

    // ---- compute-side lane constants ----
    const int p_ln  = (((r & 1) << 2) | quad) ^ ((r >> 1) & 7);
    const int aLane = wr * 2048 + (r >> 1) * 64 + p_ln * 8;           // + mf*512
    const int bLane = 16384 + wc * 2048 + (r >> 1) * 64 + p_ln * 8;   // + nf*512

#define DS_A(mf_) ds_read16(&lds[aoff + aLane + (mf_) * 512])
#define DS_B(nf_) ds_read16(&lds[boff + bLane + (nf_) * 512])

#define WAITK2 do { asm volatile("s_waitcnt lgkmcnt(2)" ::: "memory");                  \
                    __builtin_amdgcn_sched_barrier(0); } while (0)
#define WAITK0 do { asm volatile("s_waitcnt lgkmcnt(0)" ::: "memory");                  \
                    __builtin_amdgcn_sched_barrier(0); } while (0)

#define MFMA_CL(m0_, f0_, f1_)                                                          \
    __builtin_amdgcn_s_setprio(1);                                                      \
    _Pragma("unroll")                                                                   \
    for (int nf = 0; nf < 4; ++nf)                                                      \
        acc[(m0_)][nf] = __builtin_amdgcn_mfma_f32_16x16x32_bf16(f0_, bfr[nf],          \
                                                                 acc[(m0_)][nf], 0, 0, 0); \
    _Pragma("unroll")                                                                   \
    for (int nf = 0; nf < 4; ++nf)                                                      \
        acc[(m0_) + 1][nf] = __builtin_amdgcn_mfma_f32_16x16x32_bf16(f1_, bfr[nf],      \
                                                                 acc[(m0_) + 1][nf], 0, 0, 0); \
    __builtin_amdgcn_s_setprio(0);

    f32x4 acc[4][4];
#pragma unroll
    for (int mf = 0; mf < 4; ++mf)
#pragma unroll
        for (int nf = 0; nf < 4; ++nf) acc[mf][nf] = (f32x4){0.f, 0.f, 0.f, 0.f};

    // ---- prologue: stage tile0 into buf0 ----
    STAGE(0, 0);
    asm volatile("s_waitcnt vmcnt(0)" ::: "memory");
    __builtin_amdgcn_s_barrier();

    for (int t = 0; t < NT; ++t) {
        const int b    = t & 1;
        const int aoff = b * 8192;
        const int boff = b * 4096;
        const bool pf  = (t + 1 < NT);

        // stage next tile FIRST: full-tile issue->wait distance covers HBM lat
        if (pf) STAGE(b ^ 1, t + 1);

        bf16x8 bfr[4], a0, a1, a2, a3;
#pragma unroll
        for (int nf = 0; nf < 4; ++nf) bfr[nf] = DS_B(nf);
        a0 = DS_A(0); a1 = DS_A(1);
        a2 = DS_A(2); a3 = DS_A(3);

        WAITK2;                 // B0..3 + A0,A1 done; A2,A3 in flight
        MFMA_CL(0, a0, a1)

        WAITK0;                 // A2,A3 done
        MFMA_CL(2, a2, a3)

        if (pf) {
            asm volatile("s_waitcnt vmcnt(0)" ::: "memory");
            __builtin_amdgcn_s_barrier();
        }
    }

    // ---- epilogue: D[row = quad*4 + i][col = r] per 16x16 frag ----
#pragma unroll
    for (int mf = 0; mf < 4; ++mf) {
#pragma unroll
        for (int i = 0; i < 4; ++i) {
            long m = bm0 + wr * 64 + mf * 16 + quad * 4 + i;
            if (F32OUT) {
                float* crow = (float*)Cout + m * (long)N + bn0 + wc * 64 + r;
#pragma unroll
                for (int nf = 0; nf < 4; ++nf) crow[nf * 16] = acc[mf][nf][i];
            } else {
                uint16_t* crow = (uint16_t*)Cout + m * (long)N + bn0 + wc * 64 + r;
#pragma unroll
                for (int nf = 0; nf < 4; ++nf) crow[nf * 16] = f2bf(acc[mf][nf][i]);
            }
        }
    }
#undef STAGE
#undef DS_A
#undef DS_B
#undef WAITK2
#undef WAITK0
#undef MFMA_CL
}

// ---------------------------------------------------------------------------
// Local window attention, LDS-staged K/V with zero-filled halo rows,
// split-wait staging: Q (asm loads) -> K DMA -> V DMA; scores run with V
// still in flight (vmcnt(8) = Q+K done), PV after vmcnt(0).
// Block = (bn, head), 256 threads, thread = s. LDS 65.5 KB (2 blocks/CU).
// Count-safety: vmcnt(8) waits the oldest (outstanding-8) ops; K's last op
// is always covered even if the compiler interleaves extra loads (they only
// add slack). Halo ds_writes drained by lgkmcnt(0) before the barrier.
// ---------------------------------------------------------------------------
__global__ __launch_bounds__(256, 2)
void local_attn(const uint16_t* __restrict__ qkv, const float* __restrict__ pb,
                uint16_t* __restrict__ attn) {
    // [0,2096): K chunks (262 rows x 8), [2096,4192): V chunks
    __shared__ __align__(16) uint4 smem[4192];

    const int h  = blockIdx.x & 7;
    const int bn = blockIdx.x >> 3;
    const int s  = threadIdx.x;
    const int tid = threadIdx.x;
    const size_t base = (size_t)bn * 256 * 1536;

    // ---- own Q row via counted asm loads (8 x 16B) ----
    const uint16_t* qrow = qkv + base + (size_t)s * 1536 + h * 64;
    uint4 qc[8];
#pragma unroll
    for (int c = 0; c < 8; ++c) qc[c] = gload16(qrow + c * 8);

    // ---- zero-fill halo rows: 6 rows x 8 chunks x 2 arrays = 96 chunks ----
    if (tid < 96) {
        int a    = tid / 48;            // 0=K, 1=V
        int rem  = tid - a * 48;        // 0..47
        int hr6  = rem >> 3;            // 0..5
        int c8   = rem & 7;
        int hrow = (hr6 < 3) ? hr6 : (256 + hr6);  // 0,1,2,259,260,261
        smem[a * 2096 + hrow * 8 + c8] = (uint4){0u, 0u, 0u, 0u};
    }

    // ---- stage K (it 0..7) then V (it 8..15) via DMA, pre-swizzled source ----
#pragma unroll
    for (int it = 0; it < 16; ++it) {
        int i   = tid + it * 256;
        int a   = i >> 11;        // 0=K, 1=V
        int idx = i & 2047;
        int sp  = idx >> 3;
        int cs  = (i & 7) ^ ((sp + 3) & 7);
        const uint16_t* src = qkv + base + (size_t)sp * 1536 + 512 + a * 512 + h * 64 + cs * 8;
        GLOAD_LDS16(src, (uint16_t*)&smem[a * 2096 + (sp + 3) * 8 + (i & 7)]);
    }

    // Q(8) + K(8) done; V(8) still in flight. Halo ds_writes drained.
    asm volatile("s_waitcnt vmcnt(8) lgkmcnt(0)" ::: "memory");
    __builtin_amdgcn_s_barrier();
    __builtin_amdgcn_sched_barrier(0);

    // ---- scores: hrow = s+w spans [s, s+6] in [0,262), branchless ----
    float sc[7];
#pragma unroll
    for (int w = 0; w < 7; ++w) sc[w] = 0.f;

#pragma unroll
    for (int c = 0; c < 8; ++c) {
        float qf[8];
        unpack8(qc[c], qf);
        uint4 kc[7];
#pragma unroll
        for (int w = 0; w < 7; ++w) {
            int hrow = s + w;
            kc[w] = smem[hrow * 8 + (c ^ (hrow & 7))];
        }
#pragma unroll
        for (int w = 0; w < 7; ++w) {
            float kf[8];
            unpack8(kc[w], kf);
#pragma unroll
            for (int j = 0; j < 8; ++j) sc[w] += qf[j] * kf[j];
        }
    }

    const float* pbr = pb + ((size_t)h * 256 + s) * 7;
    float mx = -1e30f;
#pragma unroll
    for (int w = 0; w < 7; ++w) {
        sc[w] = sc[w] * 0.125f + pbr[w];
        mx = fmaxf(mx, sc[w]);
    }
    float p[7], sum = 0.f;
#pragma unroll
    for (int w = 0; w < 7; ++w) {
        p[w] = __expf(sc[w] - mx);
        sum += p[w];
    }
    const float inv = 1.f / sum;
#pragma unroll
    for (int w = 0; w < 7; ++w) p[w] *= inv;

    // V landed; all waves' K-phase reads done.
    asm volatile("s_waitcnt vmcnt(0)" ::: "memory");
    __builtin_amdgcn_s_barrier();
    __builtin_amdgcn_sched_barrier(0);

    // ---- output: branchless (halo V rows are zero), one 128-B store ----
    uint4 ov[8];
#pragma unroll
    for (int c = 0; c < 8; ++c) {
        uint4 vc[7];
#pragma unroll
        for (int w = 0; w < 7; ++w) {
            int hrow = s + w;
            vc[w] = smem[2096 + hrow * 8 + (c ^ (hrow & 7))];
        }
        float o[8] = {0.f, 0.f, 0.f, 0.f, 0.f, 0.f, 0.f, 0.f};
#pragma unroll
        for (int w = 0; w < 7; ++w) {
            float vf[8];
            unpack8(vc[w], vf);
#pragma unroll
            for (int j = 0; j < 8; ++j) o[j] += p[w] * vf[j];
        }
        ov[c].x = pack2(o[0], o[1]);
        ov[c].y = pack2(o[2], o[3]);
        ov[c].z = pack2(o[4], o[5]);
        ov[c].w = pack2(o[6], o[7]);
    }

    uint16_t* orow = attn + ((size_t)(bn * 256 + s)) * 512 + h * 64;
#pragma unroll
    for (int c = 0; c < 8; ++c) *(uint4*)(orow + c * 8) = ov[c];
}

// ---------------------------------------------------------------------------
extern "C" void kernel_launch(void* const* d_in, const int* in_sizes, int n_in,
                              void* d_out, int out_size, void* d_ws, size_t ws_size,
                              hipStream_t stream) {
    const float* X    = (const float*)d_in[0];  // 32768 x 512 fp32
    const float* pb   = (const float*)d_in[1];  // 8 x 256 x 7 fp32
    const float* Wqkv = (const float*)d_in[2];  // 512 x 1536 fp32
    const float* Wout = (const float*)d_in[3];  // 512 x 512 fp32
    float* out = (float*)d_out;                 // 32768 x 512 fp32

    char* ws = (char*)d_ws;
    uint16_t* WqkvT = (uint16_t*)(ws);                  // 1536x512 bf16 = 1.5 MB
    uint16_t* WoutT = (uint16_t*)(ws + 1572864);        // 512x512  bf16 = 0.5 MB
    uint16_t* qkvb  = (uint16_t*)(ws + 2097152);        // 32768x1536 bf16 = 96 MB
    uint16_t* Xb    = (uint16_t*)(ws + 102760448);      // 32768x512 bf16 = 32 MB
    uint16_t* attnb = Xb;  // alias: Xb dead after GEMM1 (stream-ordered)

    cvt_f32_bf16<<<(32768 * 512 / 8 + 255) / 256, 256, 0, stream>>>(X, Xb, 32768 * 512 / 8);
    transpose_cvt<<<(512 * 1536 + 255) / 256, 256, 0, stream>>>(Wqkv, WqkvT, 512, 1536);
    transpose_cvt<<<(512 * 512 + 255) / 256, 256, 0, stream>>>(Wout, WoutT, 512, 512);

    gemm_mn<false><<<dim3(128, 12), 512, 0, stream>>>(Xb, WqkvT, qkvb, 32768, 1536, 512);
    local_attn<<<1024, 256, 0, stream>>>(qkvb, pb, attnb);
    gemm_mn<true><<<dim3(128, 4), 512, 0, stream>>>(attnb, WoutT, out, 32768, 512, 512);
}

// Round 6
// 257.111 us; speedup vs baseline: 1.0282x; 1.0282x over previous
//
#include <hip/hip_runtime.h>
#include <hip/hip_bf16.h>
#include <cstdint>

// B=2, HW=64 -> 128 rows of S=256; M = 32768. D=512, HEADS=8, DK=64,
// 3*H*DK=1536, KSIZE=7. Inputs/outputs fp32; internal compute bf16 MFMA.

typedef __bf16 bf16x8 __attribute__((ext_vector_type(8)));
typedef float f32x4 __attribute__((ext_vector_type(4)));

__device__ __forceinline__ uint16_t f2bf(float f) {
    uint32_t u = __builtin_bit_cast(uint32_t, f);
    return (uint16_t)((u + 0x7fffu + ((u >> 16) & 1u)) >> 16);
}
__device__ __forceinline__ float bflo(uint32_t u) { return __builtin_bit_cast(float, u << 16); }
__device__ __forceinline__ float bfhi(uint32_t u) { return __builtin_bit_cast(float, u & 0xffff0000u); }

__device__ __forceinline__ void unpack8(uint4 v, float* f) {
    f[0] = bflo(v.x); f[1] = bfhi(v.x);
    f[2] = bflo(v.y); f[3] = bfhi(v.y);
    f[4] = bflo(v.z); f[5] = bfhi(v.z);
    f[6] = bflo(v.w); f[7] = bfhi(v.w);
}
__device__ __forceinline__ uint32_t pack2(float a, float b) {
    return (uint32_t)f2bf(a) | ((uint32_t)f2bf(b) << 16);
}

#define GLOAD_LDS16(gp, lp)                                                        \
    __builtin_amdgcn_global_load_lds((const __attribute__((address_space(1))) void*)(gp), \
                                     (__attribute__((address_space(3))) void*)(lp), 16, 0, 0)

// Inline-asm LDS read: invisible to the compiler's waitcnt/alias tracking.
// Volatile asm keeps mutual program order with the waitcnt/barrier asm, so the
// issue/wait counting below is exact. Caller owns lgkmcnt discipline.
__device__ __forceinline__ bf16x8 ds_read16(const uint16_t* p) {
    bf16x8 r;
    asm volatile("ds_read_b128 %0, %1"
                 : "=v"(r)
                 : "v"((const __attribute__((address_space(3))) void*)p));
    return r;
}

// Inline-asm counted global load (vmcnt accounting owned by caller).
__device__ __forceinline__ uint4 gload16(const uint16_t* p) {
    uint4 r;
    asm volatile("global_load_dwordx4 %0, %1, off"
                 : "=v"(r)
                 : "v"((const __attribute__((address_space(1))) void*)p));
    return r;
}

// ---------------------------------------------------------------------------
// fp32 -> bf16 bulk convert, 8 elems/thread
// ---------------------------------------------------------------------------
__global__ void cvt_f32_bf16(const float* __restrict__ in, uint16_t* __restrict__ out, int n8) {
    int i = blockIdx.x * 256 + threadIdx.x;
    if (i >= n8) return;
    const float4* p = (const float4*)in + (size_t)i * 2;
    float4 a = p[0], b = p[1];
    uint4 o;
    o.x = pack2(a.x, a.y);
    o.y = pack2(a.z, a.w);
    o.z = pack2(b.x, b.y);
    o.w = pack2(b.z, b.w);
    *((uint4*)out + i) = o;
}

// ---------------------------------------------------------------------------
// transpose + convert: out[c*R + r] = bf16(in[r*C + c])
// ---------------------------------------------------------------------------
__global__ void transpose_cvt(const float* __restrict__ in, uint16_t* __restrict__ out,
                              int R, int C) {
    int idx = blockIdx.x * 256 + threadIdx.x;
    if (idx >= R * C) return;
    int r = idx / C;
    int c = idx - r * C;
    out[(size_t)c * R + r] = f2bf(in[idx]);
}

// ---------------------------------------------------------------------------
// 256x128-tile bf16 GEMM, BK=32, TRIPLE-buffered LDS, counted vmcnt (T4).
// C[M,N] = A[M,K] @ B[K,N], B given transposed (BT[N,K]).
// 512 threads = 8 waves (4 M-waves x 2 N-waves), per-wave 64x64 output.
// LDS 72 KB (3 bufs x 24 KB) -> 2 blocks/CU, 4 waves/SIMD.
//
// THE round-6 change: prefetch depth 2. Tile t stages tile t+2 into buf
// (t+2)%3 and ends with s_waitcnt vmcnt(3) -- "t+1's 3 loads landed, t+2's
// 3 still in flight". vmcnt NEVER reaches 0 in the main loop, and each
// stage's issue->wait distance is ~2 tiles (~800 cyc), covering queued
// L2/HBM latency. (Rounds 3-5 waited on loads issued the SAME tile -- an
// exposed round-trip per tile; MfmaUtil pinned at ~30% in all of them.)
//
// LDS layout (per tile): rows packed 2-per-64-elem-line; 16B chunk of
// (row, c) stored at line = row>>1, p = ((row&1)*4 + c) ^ (line&7).
// ds_read_b128 frag reads hit each 4-bank group with exactly 2 lanes
// (free, m136). DMA dest linear; inverse permutation applied to the
// per-thread GLOBAL source address (both-sides rule #21).
//
// Race-safety: buf (t+2)%3 == buf (t-1)%3 was last READ in tile t-1; those
// reads drained at tile t-1's lgkmcnt(0), which precedes tile t-1's end
// barrier, which precedes tile t's stage issue. vmcnt(3) at end of t
// guarantees buf (t+1)%3 fully resident before tile t+1 reads it.
// Assumes K % 32 == 0, K/32 >= 3 (here K=512 -> NT=16).
// ---------------------------------------------------------------------------
template <bool F32OUT>
__global__ __launch_bounds__(512, 4)
void gemm_mn(const uint16_t* __restrict__ A, const uint16_t* __restrict__ BT,
             void* __restrict__ Cout, int M, int N, int K) {
    // elems: A bufs [0,24576) (3 x 8192), B bufs [24576,36864) (3 x 4096)
    __shared__ __align__(16) uint16_t lds[36864];  // 72 KB

    const int tid  = threadIdx.x;
    const int lane = tid & 63;
    const int wv   = tid >> 6;
    const int r    = lane & 15;
    const int quad = lane >> 4;
    const int wr   = wv >> 1;   // 0..3  (M wave)
    const int wc   = wv & 1;    // 0..1  (N wave)
    const long bm0 = (long)blockIdx.x * 256;
    const long bn0 = (long)blockIdx.y * 128;
    const int NT   = K >> 5;

    // ---- staging: A chunks d0=tid, d1=tid+512 (of 1024); B chunk e0=tid ----
    // chunk d -> line=d>>3, p=d&7, pre=p^(line&7), half=pre>>2, c=pre&3,
    // row=2*line+half, src col = c*8 (within the 32-elem k-slice).
#define SRC_ROWCOL(d_, row_, col_) do {                                                 \
        int ln_ = (d_) >> 3, pre_ = ((d_) & 7) ^ (ln_ & 7);                             \
        row_ = 2 * ln_ + (pre_ >> 2);                                                   \
        col_ = (pre_ & 3) * 8;                                                          \
    } while (0)
    int rA0, cA0, rA1, cA1, rB0, cB0;
    SRC_ROWCOL(tid,       rA0, cA0);
    SRC_ROWCOL(tid + 512, rA1, cA1);
    SRC_ROWCOL(tid,       rB0, cB0);
    const uint16_t* pA0 = A  + (bm0 + rA0) * (long)K + cA0;
    const uint16_t* pA1 = A  + (bm0 + rA1) * (long)K + cA1;
    const uint16_t* pB0 = BT + (bn0 + rB0) * (long)K + cB0;
#undef SRC_ROWCOL

#define STAGE(b_, t_) do {                                                              \
        GLOAD_LDS16(pA0 + (t_) * 32, &lds[(b_) * 8192 + tid * 8]);                      \
        GLOAD_LDS16(pA1 + (t_) * 32, &lds[(b_) * 8192 + (tid + 512) * 8]);              \
        GLOAD_LDS16(pB0 + (t_) * 32, &lds[24576 + (b_) * 4096 + tid * 8]);              \
    } while (0)

    // ---- compute-side lane constants ----
    const int p_ln  = (((r & 1) << 2) | quad) ^ ((r >> 1) & 7);
    const int aLane = wr * 2048 + (r >> 1) * 64 + p_ln * 8;           // + mf*512
    const int bLane = 24576 + wc * 2048 + (r >> 1) * 64 + p_ln * 8;   // + nf*512

#define DS_A(mf_) ds_read16(&lds[aoff + aLane + (mf_) * 512])
#define DS_B(nf_) ds_read16(&lds[boff + bLane + (nf_) * 512])

#define WAITK2 do { asm volatile("s_waitcnt lgkmcnt(2)" ::: "memory");                  \
                    __builtin_amdgcn_sched_barrier(0); } while (0)
#define WAITK0 do { asm volatile("s_waitcnt lgkmcnt(0)" ::: "memory");                  \
                    __builtin_amdgcn_sched_barrier(0); } while (0)

#define MFMA_CL(m0_, f0_, f1_)                                                          \
    __builtin_amdgcn_s_setprio(1);                                                      \
    _Pragma("unroll")                                                                   \
    for (int nf = 0; nf < 4; ++nf)                                                      \
        acc[(m0_)][nf] = __builtin_amdgcn_mfma_f32_16x16x32_bf16(f0_, bfr[nf],          \
                                                                 acc[(m0_)][nf], 0, 0, 0); \
    _Pragma("unroll")                                                                   \
    for (int nf = 0; nf < 4; ++nf)                                                      \
        acc[(m0_) + 1][nf] = __builtin_amdgcn_mfma_f32_16x16x32_bf16(f1_, bfr[nf],      \
                                                                 acc[(m0_) + 1][nf], 0, 0, 0); \
    __builtin_amdgcn_s_setprio(0);

    f32x4 acc[4][4];
#pragma unroll
    for (int mf = 0; mf < 4; ++mf)
#pragma unroll
        for (int nf = 0; nf < 4; ++nf) acc[mf][nf] = (f32x4){0.f, 0.f, 0.f, 0.f};

    // ---- prologue: stage tile0 -> buf0, tile1 -> buf1; wait tile0 only ----
    STAGE(0, 0);
    STAGE(1, 1);
    asm volatile("s_waitcnt vmcnt(3)" ::: "memory");   // tile0 landed, tile1 in flight
    __builtin_amdgcn_s_barrier();

    int b = 0, bs = 2;   // compute buffer (t%3), stage buffer ((t+2)%3)
    for (int t = 0; t < NT; ++t) {
        const int aoff = b * 8192;
        const int boff = b * 4096;

        // stage tile t+2 FIRST: 2-tile issue->wait distance covers HBM/L2 lat
        if (t + 2 < NT) STAGE(bs, t + 2);

        bf16x8 bfr[4], a0, a1, a2, a3;
#pragma unroll
        for (int nf = 0; nf < 4; ++nf) bfr[nf] = DS_B(nf);
        a0 = DS_A(0); a1 = DS_A(1);
        a2 = DS_A(2); a3 = DS_A(3);

        WAITK2;                 // B0..3 + A0,A1 done; A2,A3 in flight
        MFMA_CL(0, a0, a1)

        WAITK0;                 // A2,A3 done
        MFMA_CL(2, a2, a3)

        if (t + 1 < NT) {
            if (t + 2 < NT)
                asm volatile("s_waitcnt vmcnt(3)" ::: "memory");  // t+1 landed, t+2 in flight
            else
                asm volatile("s_waitcnt vmcnt(0)" ::: "memory");  // last prefetch drains
            __builtin_amdgcn_s_barrier();
        }

        b  = (b  == 2) ? 0 : b + 1;
        bs = (bs == 2) ? 0 : bs + 1;
    }

    // ---- epilogue: D[row = quad*4 + i][col = r] per 16x16 frag ----
#pragma unroll
    for (int mf = 0; mf < 4; ++mf) {
#pragma unroll
        for (int i = 0; i < 4; ++i) {
            long m = bm0 + wr * 64 + mf * 16 + quad * 4 + i;
            if (F32OUT) {
                float* crow = (float*)Cout + m * (long)N + bn0 + wc * 64 + r;
#pragma unroll
                for (int nf = 0; nf < 4; ++nf) crow[nf * 16] = acc[mf][nf][i];
            } else {
                uint16_t* crow = (uint16_t*)Cout + m * (long)N + bn0 + wc * 64 + r;
#pragma unroll
                for (int nf = 0; nf < 4; ++nf) crow[nf * 16] = f2bf(acc[mf][nf][i]);
            }
        }
    }
#undef STAGE
#undef DS_A
#undef DS_B
#undef WAITK2
#undef WAITK0
#undef MFMA_CL
}

// ---------------------------------------------------------------------------
// Local window attention, LDS-staged K/V with zero-filled halo rows,
// split-wait staging: Q (asm loads) -> K DMA -> V DMA; scores run with V
// still in flight (vmcnt(8) = Q+K done), PV after vmcnt(0).
// Block = (bn, head), 256 threads, thread = s. LDS 65.5 KB (2 blocks/CU).
// Count-safety: vmcnt(8) waits the oldest (outstanding-8) ops; K's last op
// is always covered even if the compiler interleaves extra loads (they only
// add slack). Halo ds_writes drained by lgkmcnt(0) before the barrier.
// ---------------------------------------------------------------------------
__global__ __launch_bounds__(256, 2)
void local_attn(const uint16_t* __restrict__ qkv, const float* __restrict__ pb,
                uint16_t* __restrict__ attn) {
    // [0,2096): K chunks (262 rows x 8), [2096,4192): V chunks
    __shared__ __align__(16) uint4 smem[4192];

    const int h  = blockIdx.x & 7;
    const int bn = blockIdx.x >> 3;
    const int s  = threadIdx.x;
    const int tid = threadIdx.x;
    const size_t base = (size_t)bn * 256 * 1536;

    // ---- own Q row via counted asm loads (8 x 16B) ----
    const uint16_t* qrow = qkv + base + (size_t)s * 1536 + h * 64;
    uint4 qc[8];
#pragma unroll
    for (int c = 0; c < 8; ++c) qc[c] = gload16(qrow + c * 8);

    // ---- zero-fill halo rows: 6 rows x 8 chunks x 2 arrays = 96 chunks ----
    if (tid < 96) {
        int a    = tid / 48;            // 0=K, 1=V
        int rem  = tid - a * 48;        // 0..47
        int hr6  = rem >> 3;            // 0..5
        int c8   = rem & 7;
        int hrow = (hr6 < 3) ? hr6 : (256 + hr6);  // 0,1,2,259,260,261
        smem[a * 2096 + hrow * 8 + c8] = (uint4){0u, 0u, 0u, 0u};
    }

    // ---- stage K (it 0..7) then V (it 8..15) via DMA, pre-swizzled source ----
#pragma unroll
    for (int it = 0; it < 16; ++it) {
        int i   = tid + it * 256;
        int a   = i >> 11;        // 0=K, 1=V
        int idx = i & 2047;
        int sp  = idx >> 3;
        int cs  = (i & 7) ^ ((sp + 3) & 7);
        const uint16_t* src = qkv + base + (size_t)sp * 1536 + 512 + a * 512 + h * 64 + cs * 8;
        GLOAD_LDS16(src, (uint16_t*)&smem[a * 2096 + (sp + 3) * 8 + (i & 7)]);
    }

    // Q(8) + K(8) done; V(8) still in flight. Halo ds_writes drained.
    asm volatile("s_waitcnt vmcnt(8) lgkmcnt(0)" ::: "memory");
    __builtin_amdgcn_s_barrier();
    __builtin_amdgcn_sched_barrier(0);

    // ---- scores: hrow = s+w spans [s, s+6] in [0,262), branchless ----
    float sc[7];
#pragma unroll
    for (int w = 0; w < 7; ++w) sc[w] = 0.f;

#pragma unroll
    for (int c = 0; c < 8; ++c) {
        float qf[8];
        unpack8(qc[c], qf);
        uint4 kc[7];
#pragma unroll
        for (int w = 0; w < 7; ++w) {
            int hrow = s + w;
            kc[w] = smem[hrow * 8 + (c ^ (hrow & 7))];
        }
#pragma unroll
        for (int w = 0; w < 7; ++w) {
            float kf[8];
            unpack8(kc[w], kf);
#pragma unroll
            for (int j = 0; j < 8; ++j) sc[w] += qf[j] * kf[j];
        }
    }

    const float* pbr = pb + ((size_t)h * 256 + s) * 7;
    float mx = -1e30f;
#pragma unroll
    for (int w = 0; w < 7; ++w) {
        sc[w] = sc[w] * 0.125f + pbr[w];
        mx = fmaxf(mx, sc[w]);
    }
    float p[7], sum = 0.f;
#pragma unroll
    for (int w = 0; w < 7; ++w) {
        p[w] = __expf(sc[w] - mx);
        sum += p[w];
    }
    const float inv = 1.f / sum;
#pragma unroll
    for (int w = 0; w < 7; ++w) p[w] *= inv;

    // V landed; all waves' K-phase reads done.
    asm volatile("s_waitcnt vmcnt(0)" ::: "memory");
    __builtin_amdgcn_s_barrier();
    __builtin_amdgcn_sched_barrier(0);

    // ---- output: branchless (halo V rows are zero), one 128-B store ----
    uint4 ov[8];
#pragma unroll
    for (int c = 0; c < 8; ++c) {
        uint4 vc[7];
#pragma unroll
        for (int w = 0; w < 7; ++w) {
            int hrow = s + w;
            vc[w] = smem[2096 + hrow * 8 + (c ^ (hrow & 7))];
        }
        float o[8] = {0.f, 0.f, 0.f, 0.f, 0.f, 0.f, 0.f, 0.f};
#pragma unroll
        for (int w = 0; w < 7; ++w) {
            float vf[8];
            unpack8(vc[w], vf);
#pragma unroll
            for (int j = 0; j < 8; ++j) o[j] += p[w] * vf[j];
        }
        ov[c].x = pack2(o[0], o[1]);
        ov[c].y = pack2(o[2], o[3]);
        ov[c].z = pack2(o[4], o[5]);
        ov[c].w = pack2(o[6], o[7]);
    }

    uint16_t* orow = attn + ((size_t)(bn * 256 + s)) * 512 + h * 64;
#pragma unroll
    for (int c = 0; c < 8; ++c) *(uint4*)(orow + c * 8) = ov[c];
}

// ---------------------------------------------------------------------------
extern "C" void kernel_launch(void* const* d_in, const int* in_sizes, int n_in,
                              void* d_out, int out_size, void* d_ws, size_t ws_size,
                              hipStream_t stream) {
    const float* X    = (const float*)d_in[0];  // 32768 x 512 fp32
    const float* pb   = (const float*)d_in[1];  // 8 x 256 x 7 fp32
    const float* Wqkv = (const float*)d_in[2];  // 512 x 1536 fp32
    const float* Wout = (const float*)d_in[3];  // 512 x 512 fp32
    float* out = (float*)d_out;                 // 32768 x 512 fp32

    char* ws = (char*)d_ws;
    uint16_t* WqkvT = (uint16_t*)(ws);                  // 1536x512 bf16 = 1.5 MB
    uint16_t* WoutT = (uint16_t*)(ws + 1572864);        // 512x512  bf16 = 0.5 MB
    uint16_t* qkvb  = (uint16_t*)(ws + 2097152);        // 32768x1536 bf16 = 96 MB
    uint16_t* Xb    = (uint16_t*)(ws + 102760448);      // 32768x512 bf16 = 32 MB
    uint16_t* attnb = Xb;  // alias: Xb dead after GEMM1 (stream-ordered)

    cvt_f32_bf16<<<(32768 * 512 / 8 + 255) / 256, 256, 0, stream>>>(X, Xb, 32768 * 512 / 8);
    transpose_cvt<<<(512 * 1536 + 255) / 256, 256, 0, stream>>>(Wqkv, WqkvT, 512, 1536);
    transpose_cvt<<<(512 * 512 + 255) / 256, 256, 0, stream>>>(Wout, WoutT, 512, 512);

    gemm_mn<false><<<dim3(128, 12), 512, 0, stream>>>(Xb, WqkvT, qkvb, 32768, 1536, 512);
    local_attn<<<1024, 256, 0, stream>>>(qkvb, pb, attnb);
    gemm_mn<true><<<dim3(128, 4), 512, 0, stream>>>(attnb, WoutT, out, 32768, 512, 512);
}

// Round 8
// 236.559 us; speedup vs baseline: 1.1175x; 1.0869x over previous
//
#include <hip/hip_runtime.h>
#include <hip/hip_bf16.h>
#include <cstdint>

// B=2, HW=64 -> 128 rows of S=256; M = 32768. D=512, HEADS=8, DK=64,
// 3*H*DK=1536, KSIZE=7. Inputs/outputs fp32; internal compute bf16 MFMA.
//
// Round-8 = round-7 resubmit (bench infra failed; kernel re-audited clean).
// GEMM1 (qkv projection) and local attention are FUSED: block = (bn, head)
// computes q/k/v for its 256 rows x 64 dims directly into registers
// (3 x 256x64 GEMM sharing one A-tile), spills to swizzled LDS, and runs
// score/softmax/PV in-block. The 96 MB qkv intermediate (write + read) and
// one kernel dispatch are eliminated.

typedef __bf16 bf16x8 __attribute__((ext_vector_type(8)));
typedef float f32x4 __attribute__((ext_vector_type(4)));

__device__ __forceinline__ uint16_t f2bf(float f) {
    uint32_t u = __builtin_bit_cast(uint32_t, f);
    return (uint16_t)((u + 0x7fffu + ((u >> 16) & 1u)) >> 16);
}
__device__ __forceinline__ float bflo(uint32_t u) { return __builtin_bit_cast(float, u << 16); }
__device__ __forceinline__ float bfhi(uint32_t u) { return __builtin_bit_cast(float, u & 0xffff0000u); }

__device__ __forceinline__ void unpack8(uint4 v, float* f) {
    f[0] = bflo(v.x); f[1] = bfhi(v.x);
    f[2] = bflo(v.y); f[3] = bfhi(v.y);
    f[4] = bflo(v.z); f[5] = bfhi(v.z);
    f[6] = bflo(v.w); f[7] = bfhi(v.w);
}
__device__ __forceinline__ uint32_t pack2(float a, float b) {
    return (uint32_t)f2bf(a) | ((uint32_t)f2bf(b) << 16);
}

#define GLOAD_LDS16(gp, lp)                                                        \
    __builtin_amdgcn_global_load_lds((const __attribute__((address_space(1))) void*)(gp), \
                                     (__attribute__((address_space(3))) void*)(lp), 16, 0, 0)

// Inline-asm LDS read: invisible to compiler waitcnt/alias tracking; caller
// owns lgkmcnt discipline (wait + sched_barrier(0) before consuming MFMAs).
__device__ __forceinline__ bf16x8 ds_read16(const uint16_t* p) {
    bf16x8 r;
    asm volatile("ds_read_b128 %0, %1"
                 : "=v"(r)
                 : "v"((const __attribute__((address_space(3))) void*)p));
    return r;
}

// ---------------------------------------------------------------------------
// fp32 -> bf16 bulk convert, 8 elems/thread
// ---------------------------------------------------------------------------
__global__ void cvt_f32_bf16(const float* __restrict__ in, uint16_t* __restrict__ out, int n8) {
    int i = blockIdx.x * 256 + threadIdx.x;
    if (i >= n8) return;
    const float4* p = (const float4*)in + (size_t)i * 2;
    float4 a = p[0], b = p[1];
    uint4 o;
    o.x = pack2(a.x, a.y);
    o.y = pack2(a.z, a.w);
    o.z = pack2(b.x, b.y);
    o.w = pack2(b.z, b.w);
    *((uint4*)out + i) = o;
}

// ---------------------------------------------------------------------------
// Both weight transposes in ONE launch: out[c*512 + r] = bf16(in[r*C + c]).
// Wqkv: 512x1536 -> WqkvT 1536x512; Wout: 512x512 -> WoutT 512x512.
// ---------------------------------------------------------------------------
__global__ void transpose_cvt2(const float* __restrict__ Wqkv, const float* __restrict__ Wout,
                               uint16_t* __restrict__ WqkvT, uint16_t* __restrict__ WoutT) {
    int idx = blockIdx.x * 256 + threadIdx.x;
    if (idx < 512 * 1536) {
        int r = idx / 1536, c = idx - r * 1536;
        WqkvT[(size_t)c * 512 + r] = f2bf(Wqkv[idx]);
    } else {
        idx -= 512 * 1536;
        int r = idx >> 9, c = idx & 511;
        WoutT[(size_t)c * 512 + r] = f2bf(Wout[idx]);
    }
}

// ---------------------------------------------------------------------------
// FUSED qkv-projection + local-window attention.
// Block = (bn, head): id = h*128 + bn (same-bn blocks share A and land on the
// same XCD since 128 % 8 == 0). 512 threads = 8 waves (4 M x 2 N).
//
// GEMM phase: C[256 x 192] = Xb[bn rows, 512] @ W[192 cols of WqkvT], BK=32,
// double-buffered LDS staging via global_load_lds (pre-swizzled source, linear
// dest; packed 2-rows-per-64-elem-line, chunk p = ((row&1)*4+c) ^ (line&7)).
// Wave tile 64x96: acc[4][6] (96 VGPR). Local cols: [0,64)=q [64,128)=k
// [128,192)=v of this head.
//
// Epilogue: acc -> LDS in the attention layout (q plain rows + K/V with
// 3-row zero halo, 16B-chunk XOR swizzle c ^ (row&7)), then branchless
// score/softmax/PV: thread = (s = tid&255, half = tid>>8), each half owns 4
// of the 8 d-chunks; partial scores reduced through an LDS f32 buffer;
// half 0 does softmax (+bias, *0.125) and publishes p[7]; both halves do PV
// on their chunks and store 64 B each (full 128-B row per s).
//
// LDS union (uint16 elems): gemm A [0,16384) (2x8192), B [16384,28672)
// (2x6144)  ||  attn Q [0,16384), K [16384,33152), V [33152,49920),
// P(f32) [49920,54016). 105.5 KB -> 1 block/CU (8 waves).
// ---------------------------------------------------------------------------
__global__ __launch_bounds__(512, 2)
void gemm_qkv_attn(const uint16_t* __restrict__ Xb, const uint16_t* __restrict__ WqkvT,
                   const float* __restrict__ pb, uint16_t* __restrict__ attn) {
    __shared__ __align__(16) uint16_t lds[54016];  // 105.5 KB

    constexpr int KO = 16384;   // K array (elems)
    constexpr int VO = 33152;   // V array
    constexpr int PO = 49920;   // partial/p f32 buffer

    const int tid  = threadIdx.x;
    const int lane = tid & 63;
    const int wv   = tid >> 6;
    const int r    = lane & 15;
    const int quad = lane >> 4;
    const int wr   = wv >> 1;   // 0..3  (M wave)
    const int wc   = wv & 1;    // 0..1  (N wave)
    const int h    = blockIdx.x >> 7;
    const int bn   = blockIdx.x & 127;
    const long bm0 = (long)bn * 256;
    const int NT   = 16;        // K=512 / 32

    // ---- staging maps (packed-2-rows layout, inverse swizzle on source) ----
#define SRC_ROWCOL(d_, row_, col_) do {                                                 \
        int ln_ = (d_) >> 3, pre_ = ((d_) & 7) ^ (ln_ & 7);                             \
        row_ = 2 * ln_ + (pre_ >> 2);                                                   \
        col_ = (pre_ & 3) * 8;                                                          \
    } while (0)
    int rA0, cA0, rA1, cA1, rB0, cB0, rB1, cB1;
    SRC_ROWCOL(tid,        rA0, cA0);
    SRC_ROWCOL(tid + 512,  rA1, cA1);
    SRC_ROWCOL(tid,        rB0, cB0);          // B chunks 0..511
    SRC_ROWCOL(tid + 512,  rB1, cB1);          // B chunks 512..767 (tid<256)
#undef SRC_ROWCOL
    // B local row rho -> WqkvT global row: (rho/64)*512 + h*64 + (rho%64)
    const long gB0 = ((long)(rB0 >> 6)) * 512 + h * 64 + (rB0 & 63);
    const long gB1 = ((long)(rB1 >> 6)) * 512 + h * 64 + (rB1 & 63);
    const uint16_t* pA0 = Xb + (bm0 + rA0) * 512L + cA0;
    const uint16_t* pA1 = Xb + (bm0 + rA1) * 512L + cA1;
    const uint16_t* pB0 = WqkvT + gB0 * 512 + cB0;
    const uint16_t* pB1 = WqkvT + gB1 * 512 + cB1;

#define STAGE(b_, t_) do {                                                              \
        GLOAD_LDS16(pA0 + (t_) * 32, &lds[(b_) * 8192 + tid * 8]);                      \
        GLOAD_LDS16(pA1 + (t_) * 32, &lds[(b_) * 8192 + (tid + 512) * 8]);              \
        GLOAD_LDS16(pB0 + (t_) * 32, &lds[16384 + (b_) * 6144 + tid * 8]);              \
        if (tid < 256)                                                                  \
            GLOAD_LDS16(pB1 + (t_) * 32, &lds[16384 + (b_) * 6144 + (tid + 512) * 8]);  \
    } while (0)

    // ---- compute-side lane constants ----
    const int p_ln  = (((r & 1) << 2) | quad) ^ ((r >> 1) & 7);
    const int aLane = wr * 2048 + (r >> 1) * 64 + p_ln * 8;           // + mf*512
    const int bLane = 16384 + wc * 3072 + (r >> 1) * 64 + p_ln * 8;   // + nf*512

#define DS_A(mf_) ds_read16(&lds[aoff + aLane + (mf_) * 512])
#define DS_B(nf_) ds_read16(&lds[boff + bLane + (nf_) * 512])
#define WAITK(n_) do { asm volatile("s_waitcnt lgkmcnt(" #n_ ")" ::: "memory");         \
                       __builtin_amdgcn_sched_barrier(0); } while (0)

    f32x4 acc[4][6];
#pragma unroll
    for (int mf = 0; mf < 4; ++mf)
#pragma unroll
        for (int nf = 0; nf < 6; ++nf) acc[mf][nf] = (f32x4){0.f, 0.f, 0.f, 0.f};

    // ---- prologue ----
    STAGE(0, 0);
    asm volatile("s_waitcnt vmcnt(0)" ::: "memory");
    __builtin_amdgcn_s_barrier();

    for (int t = 0; t < NT; ++t) {
        const int b    = t & 1;
        const int aoff = b * 8192;
        const int boff = b * 6144;
        const bool pf  = (t + 1 < NT);

        if (pf) STAGE(b ^ 1, t + 1);

        bf16x8 bfr[6], a0, a1, a2, a3;
#pragma unroll
        for (int nf = 0; nf < 6; ++nf) bfr[nf] = DS_B(nf);
        a0 = DS_A(0); a1 = DS_A(1);
        a2 = DS_A(2); a3 = DS_A(3);

        WAITK(2);               // B0..5 + A0,A1 done; A2,A3 in flight
        __builtin_amdgcn_s_setprio(1);
#pragma unroll
        for (int nf = 0; nf < 6; ++nf) {
            acc[0][nf] = __builtin_amdgcn_mfma_f32_16x16x32_bf16(a0, bfr[nf], acc[0][nf], 0, 0, 0);
            acc[1][nf] = __builtin_amdgcn_mfma_f32_16x16x32_bf16(a1, bfr[nf], acc[1][nf], 0, 0, 0);
        }
        __builtin_amdgcn_s_setprio(0);

        WAITK(0);               // A2,A3 done
        __builtin_amdgcn_s_setprio(1);
#pragma unroll
        for (int nf = 0; nf < 6; ++nf) {
            acc[2][nf] = __builtin_amdgcn_mfma_f32_16x16x32_bf16(a2, bfr[nf], acc[2][nf], 0, 0, 0);
            acc[3][nf] = __builtin_amdgcn_mfma_f32_16x16x32_bf16(a3, bfr[nf], acc[3][nf], 0, 0, 0);
        }
        __builtin_amdgcn_s_setprio(0);

        if (pf) {
            asm volatile("s_waitcnt vmcnt(0)" ::: "memory");
            __builtin_amdgcn_s_barrier();
        }
    }

    // ---- all waves' ds_reads/DMA drained; barrier before overwriting LDS ----
    asm volatile("s_waitcnt vmcnt(0) lgkmcnt(0)" ::: "memory");
    __builtin_amdgcn_s_barrier();

    // ---- zero-fill K/V halo rows (0,1,2,259,260,261) ----
    if (tid < 96) {
        int a    = tid / 48;
        int rem  = tid - a * 48;
        int hr6  = rem >> 3;
        int c8   = rem & 7;
        int hrow = (hr6 < 3) ? hr6 : (256 + hr6);
        ((uint4*)&lds[a ? VO : KO])[hrow * 8 + c8] = (uint4){0u, 0u, 0u, 0u};
    }

    // ---- spill acc -> attn LDS layout (q plain / K,V halo+3), swizzled ----
    // local col n = wc*96 + nf*16 + r; per (wc,nf) the target array is uniform.
#pragma unroll
    for (int nf = 0; nf < 6; ++nf) {
        int arr, d0;
        if (wc == 0) { if (nf < 4) { arr = 0; d0 = nf * 16; } else { arr = 1; d0 = (nf - 4) * 16; } }
        else         { if (nf < 2) { arr = 1; d0 = 32 + nf * 16; } else { arr = 2; d0 = (nf - 2) * 16; } }
        const int d    = d0 + r;
        const int base = (arr == 0) ? 0 : ((arr == 1) ? KO : VO);
        const int hofs = (arr == 0) ? 0 : 3;
#pragma unroll
        for (int mf = 0; mf < 4; ++mf) {
#pragma unroll
            for (int i = 0; i < 4; ++i) {
                int row  = wr * 64 + mf * 16 + quad * 4 + i;
                int rowX = row + hofs;
                int off  = base + rowX * 64 + ((((d >> 3) ^ (rowX & 7))) << 3) + (d & 7);
                lds[off] = f2bf(acc[mf][nf][i]);
            }
        }
    }
    __syncthreads();

    // ================= attention phase =================
    const int s     = tid & 255;
    const int half  = tid >> 8;
    const int cbase = half * 4;
    float* pp = (float*)&lds[PO];   // [256][8] f32

    // own q chunks (4 x 16B) from LDS
    uint4 qc[4];
    const uint4* qarr = (const uint4*)lds;
#pragma unroll
    for (int c = 0; c < 4; ++c) qc[c] = qarr[s * 8 + ((cbase + c) ^ (s & 7))];

    // partial scores over my 4 chunks
    float sc[7];
#pragma unroll
    for (int w = 0; w < 7; ++w) sc[w] = 0.f;
    const uint4* karr = (const uint4*)&lds[KO];
#pragma unroll
    for (int c = 0; c < 4; ++c) {
        float qf[8];
        unpack8(qc[c], qf);
#pragma unroll
        for (int w = 0; w < 7; ++w) {
            int hrow = s + w;
            uint4 kc = karr[hrow * 8 + ((cbase + c) ^ (hrow & 7))];
            float kf[8];
            unpack8(kc, kf);
#pragma unroll
            for (int j = 0; j < 8; ++j) sc[w] += qf[j] * kf[j];
        }
    }

    if (half == 1) {
#pragma unroll
        for (int w = 0; w < 7; ++w) pp[s * 8 + w] = sc[w];
    }
    __syncthreads();

    if (half == 0) {
        const float* pbr = pb + ((size_t)h * 256 + s) * 7;
        float mx = -1e30f, tot[7];
#pragma unroll
        for (int w = 0; w < 7; ++w) {
            tot[w] = (sc[w] + pp[s * 8 + w]) * 0.125f + pbr[w];
            mx = fmaxf(mx, tot[w]);
        }
        float sum = 0.f;
#pragma unroll
        for (int w = 0; w < 7; ++w) {
            tot[w] = __expf(tot[w] - mx);
            sum += tot[w];
        }
        const float inv = 1.f / sum;
#pragma unroll
        for (int w = 0; w < 7; ++w) pp[s * 8 + w] = tot[w] * inv;
    }
    __syncthreads();

    float p[7];
#pragma unroll
    for (int w = 0; w < 7; ++w) p[w] = pp[s * 8 + w];

    // PV on my 4 chunks; one 64-B store
    const uint4* varr = (const uint4*)&lds[VO];
    uint4 ov[4];
#pragma unroll
    for (int c = 0; c < 4; ++c) {
        float o[8] = {0.f, 0.f, 0.f, 0.f, 0.f, 0.f, 0.f, 0.f};
#pragma unroll
        for (int w = 0; w < 7; ++w) {
            int hrow = s + w;
            uint4 vc = varr[hrow * 8 + ((cbase + c) ^ (hrow & 7))];
            float vf[8];
            unpack8(vc, vf);
#pragma unroll
            for (int j = 0; j < 8; ++j) o[j] += p[w] * vf[j];
        }
        ov[c].x = pack2(o[0], o[1]);
        ov[c].y = pack2(o[2], o[3]);
        ov[c].z = pack2(o[4], o[5]);
        ov[c].w = pack2(o[6], o[7]);
    }
    uint16_t* orow = attn + ((size_t)(bn * 256 + s)) * 512 + h * 64 + cbase * 8;
#pragma unroll
    for (int c = 0; c < 4; ++c) *(uint4*)(orow + c * 8) = ov[c];
#undef STAGE
#undef DS_A
#undef DS_B
#undef WAITK
}

// ---------------------------------------------------------------------------
// 256x128-tile bf16 GEMM (round-6 structure) -- used for the output proj.
// ---------------------------------------------------------------------------
template <bool F32OUT>
__global__ __launch_bounds__(512, 4)
void gemm_mn(const uint16_t* __restrict__ A, const uint16_t* __restrict__ BT,
             void* __restrict__ Cout, int M, int N, int K) {
    __shared__ __align__(16) uint16_t lds[36864];  // 72 KB (3 bufs)

    const int tid  = threadIdx.x;
    const int lane = tid & 63;
    const int wv   = tid >> 6;
    const int r    = lane & 15;
    const int quad = lane >> 4;
    const int wr   = wv >> 1;
    const int wc   = wv & 1;
    const long bm0 = (long)blockIdx.x * 256;
    const long bn0 = (long)blockIdx.y * 128;
    const int NT   = K >> 5;

#define SRC_ROWCOL(d_, row_, col_) do {                                                 \
        int ln_ = (d_) >> 3, pre_ = ((d_) & 7) ^ (ln_ & 7);                             \
        row_ = 2 * ln_ + (pre_ >> 2);                                                   \
        col_ = (pre_ & 3) * 8;                                                          \
    } while (0)
    int rA0, cA0, rA1, cA1, rB0, cB0;
    SRC_ROWCOL(tid,       rA0, cA0);
    SRC_ROWCOL(tid + 512, rA1, cA1);
    SRC_ROWCOL(tid,       rB0, cB0);
    const uint16_t* pA0 = A  + (bm0 + rA0) * (long)K + cA0;
    const uint16_t* pA1 = A  + (bm0 + rA1) * (long)K + cA1;
    const uint16_t* pB0 = BT + (bn0 + rB0) * (long)K + cB0;
#undef SRC_ROWCOL

#define STAGE(b_, t_) do {                                                              \
        GLOAD_LDS16(pA0 + (t_) * 32, &lds[(b_) * 8192 + tid * 8]);                      \
        GLOAD_LDS16(pA1 + (t_) * 32, &lds[(b_) * 8192 + (tid + 512) * 8]);              \
        GLOAD_LDS16(pB0 + (t_) * 32, &lds[24576 + (b_) * 4096 + tid * 8]);              \
    } while (0)

    const int p_ln  = (((r & 1) << 2) | quad) ^ ((r >> 1) & 7);
    const int aLane = wr * 2048 + (r >> 1) * 64 + p_ln * 8;
    const int bLane = 24576 + wc * 2048 + (r >> 1) * 64 + p_ln * 8;

#define DS_A(mf_) ds_read16(&lds[aoff + aLane + (mf_) * 512])
#define DS_B(nf_) ds_read16(&lds[boff + bLane + (nf_) * 512])
#define WAITK2 do { asm volatile("s_waitcnt lgkmcnt(2)" ::: "memory");                  \
                    __builtin_amdgcn_sched_barrier(0); } while (0)
#define WAITK0 do { asm volatile("s_waitcnt lgkmcnt(0)" ::: "memory");                  \
                    __builtin_amdgcn_sched_barrier(0); } while (0)
#define MFMA_CL(m0_, f0_, f1_)                                                          \
    __builtin_amdgcn_s_setprio(1);                                                      \
    _Pragma("unroll")                                                                   \
    for (int nf = 0; nf < 4; ++nf)                                                      \
        acc[(m0_)][nf] = __builtin_amdgcn_mfma_f32_16x16x32_bf16(f0_, bfr[nf],          \
                                                                 acc[(m0_)][nf], 0, 0, 0); \
    _Pragma("unroll")                                                                   \
    for (int nf = 0; nf < 4; ++nf)                                                      \
        acc[(m0_) + 1][nf] = __builtin_amdgcn_mfma_f32_16x16x32_bf16(f1_, bfr[nf],      \
                                                                 acc[(m0_) + 1][nf], 0, 0, 0); \
    __builtin_amdgcn_s_setprio(0);

    f32x4 acc[4][4];
#pragma unroll
    for (int mf = 0; mf < 4; ++mf)
#pragma unroll
        for (int nf = 0; nf < 4; ++nf) acc[mf][nf] = (f32x4){0.f, 0.f, 0.f, 0.f};

    STAGE(0, 0);
    STAGE(1, 1);
    asm volatile("s_waitcnt vmcnt(3)" ::: "memory");
    __builtin_amdgcn_s_barrier();

    int b = 0, bs = 2;
    for (int t = 0; t < NT; ++t) {
        const int aoff = b * 8192;
        const int boff = b * 4096;

        if (t + 2 < NT) STAGE(bs, t + 2);

        bf16x8 bfr[4], a0, a1, a2, a3;
#pragma unroll
        for (int nf = 0; nf < 4; ++nf) bfr[nf] = DS_B(nf);
        a0 = DS_A(0); a1 = DS_A(1);
        a2 = DS_A(2); a3 = DS_A(3);

        WAITK2;
        MFMA_CL(0, a0, a1)
        WAITK0;
        MFMA_CL(2, a2, a3)

        if (t + 1 < NT) {
            if (t + 2 < NT)
                asm volatile("s_waitcnt vmcnt(3)" ::: "memory");
            else
                asm volatile("s_waitcnt vmcnt(0)" ::: "memory");
            __builtin_amdgcn_s_barrier();
        }
        b  = (b  == 2) ? 0 : b + 1;
        bs = (bs == 2) ? 0 : bs + 1;
    }

#pragma unroll
    for (int mf = 0; mf < 4; ++mf) {
#pragma unroll
        for (int i = 0; i < 4; ++i) {
            long m = bm0 + wr * 64 + mf * 16 + quad * 4 + i;
            if (F32OUT) {
                float* crow = (float*)Cout + m * (long)N + bn0 + wc * 64 + r;
#pragma unroll
                for (int nf = 0; nf < 4; ++nf) crow[nf * 16] = acc[mf][nf][i];
            } else {
                uint16_t* crow = (uint16_t*)Cout + m * (long)N + bn0 + wc * 64 + r;
#pragma unroll
                for (int nf = 0; nf < 4; ++nf) crow[nf * 16] = f2bf(acc[mf][nf][i]);
            }
        }
    }
#undef STAGE
#undef DS_A
#undef DS_B
#undef WAITK2
#undef WAITK0
#undef MFMA_CL
}

// ---------------------------------------------------------------------------
extern "C" void kernel_launch(void* const* d_in, const int* in_sizes, int n_in,
                              void* d_out, int out_size, void* d_ws, size_t ws_size,
                              hipStream_t stream) {
    const float* X    = (const float*)d_in[0];  // 32768 x 512 fp32
    const float* pb   = (const float*)d_in[1];  // 8 x 256 x 7 fp32
    const float* Wqkv = (const float*)d_in[2];  // 512 x 1536 fp32
    const float* Wout = (const float*)d_in[3];  // 512 x 512 fp32
    float* out = (float*)d_out;                 // 32768 x 512 fp32

    char* ws = (char*)d_ws;
    uint16_t* WqkvT = (uint16_t*)(ws);                  // 1536x512 bf16 = 1.5 MB
    uint16_t* WoutT = (uint16_t*)(ws + 1572864);        // 512x512  bf16 = 0.5 MB
    uint16_t* Xb    = (uint16_t*)(ws + 2097152);        // 32768x512 bf16 = 32 MB
    uint16_t* attnb = (uint16_t*)(ws + 35651584);       // 32768x512 bf16 = 32 MB

    cvt_f32_bf16<<<(32768 * 512 / 8 + 255) / 256, 256, 0, stream>>>(X, Xb, 32768 * 512 / 8);
    transpose_cvt2<<<(512 * 2048 + 255) / 256, 256, 0, stream>>>(Wqkv, Wout, WqkvT, WoutT);

    gemm_qkv_attn<<<1024, 512, 0, stream>>>(Xb, WqkvT, pb, attnb);
    gemm_mn<true><<<dim3(128, 4), 512, 0, stream>>>(attnb, WoutT, out, 32768, 512, 512);
}

// Round 9
// 228.492 us; speedup vs baseline: 1.1570x; 1.0353x over previous
//
#include <hip/hip_runtime.h>
#include <hip/hip_bf16.h>
#include <cstdint>

// B=2, HW=64 -> 128 rows of S=256; M = 32768. D=512, HEADS=8, DK=64,
// 3*H*DK=1536, KSIZE=7. Inputs/outputs fp32; internal compute bf16 MFMA.
//
// Round-9: (a) fused kernel computes C^T via swapped MFMA operands so the
// acc->LDS spill is 24x ds_write_b64 per thread (was 96x scalar b16 with
// 2.24M bank conflicts); (b) gemm_mn same swap -> contiguous dwordx4
// C-stores; (c) cvt + weight transposes merged into one prep dispatch
// (4 -> 3 launches; ~20us/launch overhead measured).

typedef __bf16 bf16x8 __attribute__((ext_vector_type(8)));
typedef float f32x4 __attribute__((ext_vector_type(4)));

__device__ __forceinline__ uint16_t f2bf(float f) {
    uint32_t u = __builtin_bit_cast(uint32_t, f);
    return (uint16_t)((u + 0x7fffu + ((u >> 16) & 1u)) >> 16);
}
__device__ __forceinline__ float bflo(uint32_t u) { return __builtin_bit_cast(float, u << 16); }
__device__ __forceinline__ float bfhi(uint32_t u) { return __builtin_bit_cast(float, u & 0xffff0000u); }

__device__ __forceinline__ void unpack8(uint4 v, float* f) {
    f[0] = bflo(v.x); f[1] = bfhi(v.x);
    f[2] = bflo(v.y); f[3] = bfhi(v.y);
    f[4] = bflo(v.z); f[5] = bfhi(v.z);
    f[6] = bflo(v.w); f[7] = bfhi(v.w);
}
__device__ __forceinline__ uint32_t pack2(float a, float b) {
    return (uint32_t)f2bf(a) | ((uint32_t)f2bf(b) << 16);
}

#define GLOAD_LDS16(gp, lp)                                                        \
    __builtin_amdgcn_global_load_lds((const __attribute__((address_space(1))) void*)(gp), \
                                     (__attribute__((address_space(3))) void*)(lp), 16, 0, 0)

// Inline-asm LDS read: invisible to compiler waitcnt/alias tracking; caller
// owns lgkmcnt discipline (wait + sched_barrier(0) before consuming MFMAs).
__device__ __forceinline__ bf16x8 ds_read16(const uint16_t* p) {
    bf16x8 r;
    asm volatile("ds_read_b128 %0, %1"
                 : "=v"(r)
                 : "v"((const __attribute__((address_space(3))) void*)p));
    return r;
}

// ---------------------------------------------------------------------------
// prep: fp32->bf16 bulk convert of X (blocks [0,8192)) + both weight
// transposes (blocks [8192,12288)) in ONE dispatch.
// ---------------------------------------------------------------------------
__global__ void prep(const float* __restrict__ X, const float* __restrict__ Wqkv,
                     const float* __restrict__ Wout, uint16_t* __restrict__ Xb,
                     uint16_t* __restrict__ WqkvT, uint16_t* __restrict__ WoutT) {
    int b = blockIdx.x;
    if (b < 8192) {
        int i = b * 256 + threadIdx.x;          // 8 elems each, 2,097,152 items
        const float4* p = (const float4*)X + (size_t)i * 2;
        float4 a = p[0], q = p[1];
        uint4 o;
        o.x = pack2(a.x, a.y);
        o.y = pack2(a.z, a.w);
        o.z = pack2(q.x, q.y);
        o.w = pack2(q.z, q.w);
        *((uint4*)Xb + i) = o;
    } else {
        int idx = (b - 8192) * 256 + threadIdx.x;
        if (idx < 512 * 1536) {
            int r = idx / 1536, c = idx - r * 1536;
            WqkvT[(size_t)c * 512 + r] = f2bf(Wqkv[idx]);
        } else {
            idx -= 512 * 1536;
            int r = idx >> 9, c = idx & 511;
            WoutT[(size_t)c * 512 + r] = f2bf(Wout[idx]);
        }
    }
}

// ---------------------------------------------------------------------------
// FUSED qkv-projection + local-window attention.
// Block = (bn, head): id = h*128 + bn ((h*128+bn)%8 == bn%8, so all 8 head-
// blocks of one bn land on the same XCD -> shared A-tile is L2-local).
// 512 threads = 8 waves (4 M x 2 N).
//
// GEMM phase computes C^T: acc[mf][nf] = mfma(bfr[nf], af[mf], .) so the
// D-layout gives m = r (lane&15) and n = quad*4 + reg -- 4 CONSECUTIVE
// d-values per register quad. Spill to the attn LDS layout is then one
// ds_write_b64 per (mf,nf) frag (24 per thread), 8B-aligned, conflict-light.
//
// Attn epilogue (unchanged): q plain rows + K/V with 3-row zero halo, 16B
// chunk XOR swizzle c ^ (row&7); thread = (s, half), each half owns 4 of 8
// d-chunks; partial scores reduced via LDS f32 buffer; branchless window.
//
// LDS union (uint16 elems): gemm A [0,16384) (2x8192), B [16384,28672)
// (2x6144)  ||  attn Q [0,16384), K [16384,33152), V [33152,49920),
// P(f32) [49920,54016). 105.5 KB -> 1 block/CU (8 waves).
// ---------------------------------------------------------------------------
__global__ __launch_bounds__(512, 2)
void gemm_qkv_attn(const uint16_t* __restrict__ Xb, const uint16_t* __restrict__ WqkvT,
                   const float* __restrict__ pb, uint16_t* __restrict__ attn) {
    __shared__ __align__(16) uint16_t lds[54016];  // 105.5 KB

    constexpr int KO = 16384;   // K array (elems)
    constexpr int VO = 33152;   // V array
    constexpr int PO = 49920;   // partial/p f32 buffer

    const int tid  = threadIdx.x;
    const int lane = tid & 63;
    const int wv   = tid >> 6;
    const int r    = lane & 15;
    const int quad = lane >> 4;
    const int wr   = wv >> 1;   // 0..3  (M wave)
    const int wc   = wv & 1;    // 0..1  (N wave)
    const int h    = blockIdx.x >> 7;
    const int bn   = blockIdx.x & 127;
    const long bm0 = (long)bn * 256;
    const int NT   = 16;        // K=512 / 32

    // ---- staging maps (packed-2-rows layout, inverse swizzle on source) ----
#define SRC_ROWCOL(d_, row_, col_) do {                                                 \
        int ln_ = (d_) >> 3, pre_ = ((d_) & 7) ^ (ln_ & 7);                             \
        row_ = 2 * ln_ + (pre_ >> 2);                                                   \
        col_ = (pre_ & 3) * 8;                                                          \
    } while (0)
    int rA0, cA0, rA1, cA1, rB0, cB0, rB1, cB1;
    SRC_ROWCOL(tid,        rA0, cA0);
    SRC_ROWCOL(tid + 512,  rA1, cA1);
    SRC_ROWCOL(tid,        rB0, cB0);          // B chunks 0..511
    SRC_ROWCOL(tid + 512,  rB1, cB1);          // B chunks 512..767 (tid<256)
#undef SRC_ROWCOL
    // B local row rho -> WqkvT global row: (rho/64)*512 + h*64 + (rho%64)
    const long gB0 = ((long)(rB0 >> 6)) * 512 + h * 64 + (rB0 & 63);
    const long gB1 = ((long)(rB1 >> 6)) * 512 + h * 64 + (rB1 & 63);
    const uint16_t* pA0 = Xb + (bm0 + rA0) * 512L + cA0;
    const uint16_t* pA1 = Xb + (bm0 + rA1) * 512L + cA1;
    const uint16_t* pB0 = WqkvT + gB0 * 512 + cB0;
    const uint16_t* pB1 = WqkvT + gB1 * 512 + cB1;

#define STAGE(b_, t_) do {                                                              \
        GLOAD_LDS16(pA0 + (t_) * 32, &lds[(b_) * 8192 + tid * 8]);                      \
        GLOAD_LDS16(pA1 + (t_) * 32, &lds[(b_) * 8192 + (tid + 512) * 8]);              \
        GLOAD_LDS16(pB0 + (t_) * 32, &lds[16384 + (b_) * 6144 + tid * 8]);              \
        if (tid < 256)                                                                  \
            GLOAD_LDS16(pB1 + (t_) * 32, &lds[16384 + (b_) * 6144 + (tid + 512) * 8]);  \
    } while (0)

    // ---- compute-side lane constants ----
    const int p_ln  = (((r & 1) << 2) | quad) ^ ((r >> 1) & 7);
    const int aLane = wr * 2048 + (r >> 1) * 64 + p_ln * 8;           // + mf*512
    const int bLane = 16384 + wc * 3072 + (r >> 1) * 64 + p_ln * 8;   // + nf*512

#define DS_A(mf_) ds_read16(&lds[aoff + aLane + (mf_) * 512])
#define DS_B(nf_) ds_read16(&lds[boff + bLane + (nf_) * 512])
#define WAITK(n_) do { asm volatile("s_waitcnt lgkmcnt(" #n_ ")" ::: "memory");         \
                       __builtin_amdgcn_sched_barrier(0); } while (0)

    f32x4 acc[4][6];
#pragma unroll
    for (int mf = 0; mf < 4; ++mf)
#pragma unroll
        for (int nf = 0; nf < 6; ++nf) acc[mf][nf] = (f32x4){0.f, 0.f, 0.f, 0.f};

    // ---- prologue ----
    STAGE(0, 0);
    asm volatile("s_waitcnt vmcnt(0)" ::: "memory");
    __builtin_amdgcn_s_barrier();

    for (int t = 0; t < NT; ++t) {
        const int b    = t & 1;
        const int aoff = b * 8192;
        const int boff = b * 6144;
        const bool pf  = (t + 1 < NT);

        if (pf) STAGE(b ^ 1, t + 1);

        bf16x8 bfr[6], a0, a1, a2, a3;
#pragma unroll
        for (int nf = 0; nf < 6; ++nf) bfr[nf] = DS_B(nf);
        a0 = DS_A(0); a1 = DS_A(1);
        a2 = DS_A(2); a3 = DS_A(3);

        WAITK(2);               // B0..5 + A0,A1 done; A2,A3 in flight
        __builtin_amdgcn_s_setprio(1);
#pragma unroll
        for (int nf = 0; nf < 6; ++nf) {
            // swapped operands: acc = C^T frag (m = lane&15, n = quad*4+reg)
            acc[0][nf] = __builtin_amdgcn_mfma_f32_16x16x32_bf16(bfr[nf], a0, acc[0][nf], 0, 0, 0);
            acc[1][nf] = __builtin_amdgcn_mfma_f32_16x16x32_bf16(bfr[nf], a1, acc[1][nf], 0, 0, 0);
        }
        __builtin_amdgcn_s_setprio(0);

        WAITK(0);               // A2,A3 done
        __builtin_amdgcn_s_setprio(1);
#pragma unroll
        for (int nf = 0; nf < 6; ++nf) {
            acc[2][nf] = __builtin_amdgcn_mfma_f32_16x16x32_bf16(bfr[nf], a2, acc[2][nf], 0, 0, 0);
            acc[3][nf] = __builtin_amdgcn_mfma_f32_16x16x32_bf16(bfr[nf], a3, acc[3][nf], 0, 0, 0);
        }
        __builtin_amdgcn_s_setprio(0);

        if (pf) {
            asm volatile("s_waitcnt vmcnt(0)" ::: "memory");
            __builtin_amdgcn_s_barrier();
        }
    }

    // ---- all waves' ds_reads/DMA drained; barrier before overwriting LDS ----
    asm volatile("s_waitcnt vmcnt(0) lgkmcnt(0)" ::: "memory");
    __builtin_amdgcn_s_barrier();

    // ---- zero-fill K/V halo rows (0,1,2,259,260,261) ----
    if (tid < 96) {
        int a    = tid / 48;
        int rem  = tid - a * 48;
        int hr6  = rem >> 3;
        int c8   = rem & 7;
        int hrow = (hr6 < 3) ? hr6 : (256 + hr6);
        ((uint4*)&lds[a ? VO : KO])[hrow * 8 + c8] = (uint4){0u, 0u, 0u, 0u};
    }

    // ---- spill acc -> attn LDS layout, ONE ds_write_b64 per (mf,nf) frag ----
    // m = wr*64 + mf*16 + r;  n(d) = d0(wc,nf) + quad*4 + reg(0..3).
#pragma unroll
    for (int nf = 0; nf < 6; ++nf) {
        int arr, d0;
        if (wc == 0) { if (nf < 4) { arr = 0; d0 = nf * 16; } else { arr = 1; d0 = (nf - 4) * 16; } }
        else         { if (nf < 2) { arr = 1; d0 = 32 + nf * 16; } else { arr = 2; d0 = (nf - 2) * 16; } }
        const int base = (arr == 0) ? 0 : ((arr == 1) ? KO : VO);
        const int hofs = (arr == 0) ? 0 : 3;
        const int cc0  = (d0 >> 3) + (quad >> 1);   // 16B-chunk index of this quad's d
        const int sub  = (quad & 1) * 4;            // elem offset within chunk
#pragma unroll
        for (int mf = 0; mf < 4; ++mf) {
            int rowX = wr * 64 + mf * 16 + r + hofs;
            uint2 w;
            w.x = pack2(acc[mf][nf][0], acc[mf][nf][1]);
            w.y = pack2(acc[mf][nf][2], acc[mf][nf][3]);
            *(uint2*)&lds[base + rowX * 64 + ((cc0 ^ (rowX & 7)) << 3) + sub] = w;
        }
    }
    __syncthreads();

    // ================= attention phase =================
    const int s     = tid & 255;
    const int half  = tid >> 8;
    const int cbase = half * 4;
    float* pp = (float*)&lds[PO];   // [256][8] f32

    // own q chunks (4 x 16B) from LDS
    uint4 qc[4];
    const uint4* qarr = (const uint4*)lds;
#pragma unroll
    for (int c = 0; c < 4; ++c) qc[c] = qarr[s * 8 + ((cbase + c) ^ (s & 7))];

    // partial scores over my 4 chunks
    float sc[7];
#pragma unroll
    for (int w = 0; w < 7; ++w) sc[w] = 0.f;
    const uint4* karr = (const uint4*)&lds[KO];
#pragma unroll
    for (int c = 0; c < 4; ++c) {
        float qf[8];
        unpack8(qc[c], qf);
#pragma unroll
        for (int w = 0; w < 7; ++w) {
            int hrow = s + w;
            uint4 kc = karr[hrow * 8 + ((cbase + c) ^ (hrow & 7))];
            float kf[8];
            unpack8(kc, kf);
#pragma unroll
            for (int j = 0; j < 8; ++j) sc[w] += qf[j] * kf[j];
        }
    }

    if (half == 1) {
#pragma unroll
        for (int w = 0; w < 7; ++w) pp[s * 8 + w] = sc[w];
    }
    __syncthreads();

    if (half == 0) {
        const float* pbr = pb + ((size_t)h * 256 + s) * 7;
        float mx = -1e30f, tot[7];
#pragma unroll
        for (int w = 0; w < 7; ++w) {
            tot[w] = (sc[w] + pp[s * 8 + w]) * 0.125f + pbr[w];
            mx = fmaxf(mx, tot[w]);
        }
        float sum = 0.f;
#pragma unroll
        for (int w = 0; w < 7; ++w) {
            tot[w] = __expf(tot[w] - mx);
            sum += tot[w];
        }
        const float inv = 1.f / sum;
#pragma unroll
        for (int w = 0; w < 7; ++w) pp[s * 8 + w] = tot[w] * inv;
    }
    __syncthreads();

    float p[7];
#pragma unroll
    for (int w = 0; w < 7; ++w) p[w] = pp[s * 8 + w];

    // PV on my 4 chunks; one 64-B store
    const uint4* varr = (const uint4*)&lds[VO];
    uint4 ov[4];
#pragma unroll
    for (int c = 0; c < 4; ++c) {
        float o[8] = {0.f, 0.f, 0.f, 0.f, 0.f, 0.f, 0.f, 0.f};
#pragma unroll
        for (int w = 0; w < 7; ++w) {
            int hrow = s + w;
            uint4 vc = varr[hrow * 8 + ((cbase + c) ^ (hrow & 7))];
            float vf[8];
            unpack8(vc, vf);
#pragma unroll
            for (int j = 0; j < 8; ++j) o[j] += p[w] * vf[j];
        }
        ov[c].x = pack2(o[0], o[1]);
        ov[c].y = pack2(o[2], o[3]);
        ov[c].z = pack2(o[4], o[5]);
        ov[c].w = pack2(o[6], o[7]);
    }
    uint16_t* orow = attn + ((size_t)(bn * 256 + s)) * 512 + h * 64 + cbase * 8;
#pragma unroll
    for (int c = 0; c < 4; ++c) *(uint4*)(orow + c * 8) = ov[c];
#undef STAGE
#undef DS_A
#undef DS_B
#undef WAITK
}

// ---------------------------------------------------------------------------
// 256x128-tile bf16 GEMM (round-6 pipeline) with swapped-operand MFMA:
// C^T frags -> each lane stores 4 CONSECUTIVE n-values = one dwordx4 (f32)
// or one 8B store (bf16). Used for the output projection.
// ---------------------------------------------------------------------------
template <bool F32OUT>
__global__ __launch_bounds__(512, 4)
void gemm_mn(const uint16_t* __restrict__ A, const uint16_t* __restrict__ BT,
             void* __restrict__ Cout, int M, int N, int K) {
    __shared__ __align__(16) uint16_t lds[36864];  // 72 KB (3 bufs)

    const int tid  = threadIdx.x;
    const int lane = tid & 63;
    const int wv   = tid >> 6;
    const int r    = lane & 15;
    const int quad = lane >> 4;
    const int wr   = wv >> 1;
    const int wc   = wv & 1;
    const long bm0 = (long)blockIdx.x * 256;
    const long bn0 = (long)blockIdx.y * 128;
    const int NT   = K >> 5;

#define SRC_ROWCOL(d_, row_, col_) do {                                                 \
        int ln_ = (d_) >> 3, pre_ = ((d_) & 7) ^ (ln_ & 7);                             \
        row_ = 2 * ln_ + (pre_ >> 2);                                                   \
        col_ = (pre_ & 3) * 8;                                                          \
    } while (0)
    int rA0, cA0, rA1, cA1, rB0, cB0;
    SRC_ROWCOL(tid,       rA0, cA0);
    SRC_ROWCOL(tid + 512, rA1, cA1);
    SRC_ROWCOL(tid,       rB0, cB0);
    const uint16_t* pA0 = A  + (bm0 + rA0) * (long)K + cA0;
    const uint16_t* pA1 = A  + (bm0 + rA1) * (long)K + cA1;
    const uint16_t* pB0 = BT + (bn0 + rB0) * (long)K + cB0;
#undef SRC_ROWCOL

#define STAGE(b_, t_) do {                                                              \
        GLOAD_LDS16(pA0 + (t_) * 32, &lds[(b_) * 8192 + tid * 8]);                      \
        GLOAD_LDS16(pA1 + (t_) * 32, &lds[(b_) * 8192 + (tid + 512) * 8]);              \
        GLOAD_LDS16(pB0 + (t_) * 32, &lds[24576 + (b_) * 4096 + tid * 8]);              \
    } while (0)

    const int p_ln  = (((r & 1) << 2) | quad) ^ ((r >> 1) & 7);
    const int aLane = wr * 2048 + (r >> 1) * 64 + p_ln * 8;
    const int bLane = 24576 + wc * 2048 + (r >> 1) * 64 + p_ln * 8;

#define DS_A(mf_) ds_read16(&lds[aoff + aLane + (mf_) * 512])
#define DS_B(nf_) ds_read16(&lds[boff + bLane + (nf_) * 512])
#define WAITK2 do { asm volatile("s_waitcnt lgkmcnt(2)" ::: "memory");                  \
                    __builtin_amdgcn_sched_barrier(0); } while (0)
#define WAITK0 do { asm volatile("s_waitcnt lgkmcnt(0)" ::: "memory");                  \
                    __builtin_amdgcn_sched_barrier(0); } while (0)
#define MFMA_CL(m0_, f0_, f1_)                                                          \
    __builtin_amdgcn_s_setprio(1);                                                      \
    _Pragma("unroll")                                                                   \
    for (int nf = 0; nf < 4; ++nf)                                                      \
        acc[(m0_)][nf] = __builtin_amdgcn_mfma_f32_16x16x32_bf16(bfr[nf], f0_,          \
                                                                 acc[(m0_)][nf], 0, 0, 0); \
    _Pragma("unroll")                                                                   \
    for (int nf = 0; nf < 4; ++nf)                                                      \
        acc[(m0_) + 1][nf] = __builtin_amdgcn_mfma_f32_16x16x32_bf16(bfr[nf], f1_,      \
                                                                 acc[(m0_) + 1][nf], 0, 0, 0); \
    __builtin_amdgcn_s_setprio(0);

    f32x4 acc[4][4];
#pragma unroll
    for (int mf = 0; mf < 4; ++mf)
#pragma unroll
        for (int nf = 0; nf < 4; ++nf) acc[mf][nf] = (f32x4){0.f, 0.f, 0.f, 0.f};

    STAGE(0, 0);
    STAGE(1, 1);
    asm volatile("s_waitcnt vmcnt(3)" ::: "memory");
    __builtin_amdgcn_s_barrier();

    int b = 0, bs = 2;
    for (int t = 0; t < NT; ++t) {
        const int aoff = b * 8192;
        const int boff = b * 4096;

        if (t + 2 < NT) STAGE(bs, t + 2);

        bf16x8 bfr[4], a0, a1, a2, a3;
#pragma unroll
        for (int nf = 0; nf < 4; ++nf) bfr[nf] = DS_B(nf);
        a0 = DS_A(0); a1 = DS_A(1);
        a2 = DS_A(2); a3 = DS_A(3);

        WAITK2;
        MFMA_CL(0, a0, a1)
        WAITK0;
        MFMA_CL(2, a2, a3)

        if (t + 1 < NT) {
            if (t + 2 < NT)
                asm volatile("s_waitcnt vmcnt(3)" ::: "memory");
            else
                asm volatile("s_waitcnt vmcnt(0)" ::: "memory");
            __builtin_amdgcn_s_barrier();
        }
        b  = (b  == 2) ? 0 : b + 1;
        bs = (bs == 2) ? 0 : bs + 1;
    }

    // ---- epilogue: C^T frag -> m = r (lane), n = quad*4 + reg (contiguous) ----
#pragma unroll
    for (int mf = 0; mf < 4; ++mf) {
        long m = bm0 + wr * 64 + mf * 16 + r;
#pragma unroll
        for (int nf = 0; nf < 4; ++nf) {
            long n0 = bn0 + wc * 64 + nf * 16 + quad * 4;
            if (F32OUT) {
                float4 v = {acc[mf][nf][0], acc[mf][nf][1], acc[mf][nf][2], acc[mf][nf][3]};
                *(float4*)((float*)Cout + m * (long)N + n0) = v;
            } else {
                uint2 w;
                w.x = pack2(acc[mf][nf][0], acc[mf][nf][1]);
                w.y = pack2(acc[mf][nf][2], acc[mf][nf][3]);
                *(uint2*)((uint16_t*)Cout + m * (long)N + n0) = w;
            }
        }
    }
#undef STAGE
#undef DS_A
#undef DS_B
#undef WAITK2
#undef WAITK0
#undef MFMA_CL
}

// ---------------------------------------------------------------------------
extern "C" void kernel_launch(void* const* d_in, const int* in_sizes, int n_in,
                              void* d_out, int out_size, void* d_ws, size_t ws_size,
                              hipStream_t stream) {
    const float* X    = (const float*)d_in[0];  // 32768 x 512 fp32
    const float* pb   = (const float*)d_in[1];  // 8 x 256 x 7 fp32
    const float* Wqkv = (const float*)d_in[2];  // 512 x 1536 fp32
    const float* Wout = (const float*)d_in[3];  // 512 x 512 fp32
    float* out = (float*)d_out;                 // 32768 x 512 fp32

    char* ws = (char*)d_ws;
    uint16_t* WqkvT = (uint16_t*)(ws);                  // 1536x512 bf16 = 1.5 MB
    uint16_t* WoutT = (uint16_t*)(ws + 1572864);        // 512x512  bf16 = 0.5 MB
    uint16_t* Xb    = (uint16_t*)(ws + 2097152);        // 32768x512 bf16 = 32 MB
    uint16_t* attnb = (uint16_t*)(ws + 35651584);       // 32768x512 bf16 = 32 MB

    prep<<<12288, 256, 0, stream>>>(X, Wqkv, Wout, Xb, WqkvT, WoutT);
    gemm_qkv_attn<<<1024, 512, 0, stream>>>(Xb, WqkvT, pb, attnb);
    gemm_mn<true><<<dim3(128, 4), 512, 0, stream>>>(attnb, WoutT, out, 32768, 512, 512);
}